// Round 7
// baseline (254.217 us; speedup 1.0000x reference)
//
#include <hip/hip_runtime.h>
#include <hip/hip_bf16.h>

typedef __attribute__((ext_vector_type(8))) __bf16 bf16x8;
typedef __attribute__((ext_vector_type(4))) float f32x4;
typedef __attribute__((ext_vector_type(4))) unsigned short u16x4;

#define STATE_DIM 28224
#define NEP 8192
#define MPAD 8320          // 65 * 128
#define KSPLIT 7
#define KSTEPS 63          // 28224 / (7*64)
#define BK 64
#define EPSK 0.001f
#define CC 0.001f

// ws layout
#define WT_BYTES   (441 * 8192 * 2)                  // 7,225,344 (swizzled bf16 chunks)
#define PART_BYTES (KSPLIT * MPAD * 128 * 4)         // 29,818,880
#define Z_BYTES    (MPAD * 32 * 4)                   // 1,064,960
#define DIST_BYTES (NEP * 4)
#define WS_NEEDED  (WT_BYTES + PART_BYTES + Z_BYTES + DIST_BYTES)

__device__ __forceinline__ unsigned short f2bf(float f) {
    unsigned int u = __float_as_uint(f);
    u += 0x7fffu + ((u >> 16) & 1u);   // RNE
    return (unsigned short)(u >> 16);
}

__device__ __forceinline__ void glds16(const void* g, void* l) {
    __builtin_amdgcn_global_load_lds(
        (const __attribute__((address_space(1))) unsigned int*)g,
        (__attribute__((address_space(3))) unsigned int*)l, 16, 0, 0);
}

// ---------------- kernel 0: W1 [28224][128] f32 -> WtS: 441 chunks of 16KB,
// chunk = swizzled bf16 image of B-tile [n=0..127][k=0..63],
// byte addr within chunk = (n*128 + k*2) ^ ((n&7)<<4)  (matches gemm ds_read swizzle)
__global__ __launch_bounds__(256) void prep_wt(const float* __restrict__ W1,
                                               unsigned short* __restrict__ WtS) {
    __shared__ __align__(16) unsigned short img[8192];
    const int c = blockIdx.x;          // 441 k-tiles
    const int tid = threadIdx.x;
    const int k0 = c * 64;
#pragma unroll
    for (int i = 0; i < 32; ++i) {
        const int f = i * 256 + tid;   // f = k*128 + n
        const int k = f >> 7, n = f & 127;
        const float wv = W1[(size_t)(k0 + k) * 128 + n];
        const int ad = ((n * 128 + k * 2) ^ ((n & 7) << 4)) >> 1;  // u16 index
        img[ad] = f2bf(wv);
    }
    __syncthreads();
    unsigned short* dst = WtS + (size_t)c * 8192;
#pragma unroll
    for (int i = 0; i < 4; ++i) {
        const int f = i * 256 + tid;   // 16B unit, 1024 total
        *reinterpret_cast<uint4*>(dst + f * 8) =
            *reinterpret_cast<const uint4*>(img + f * 8);
    }
}

// ---------------- kernel 1: split-K bf16 MFMA GEMM, counted-vmcnt pipeline ----------------
// grid = 65 Mtiles * 7 Ksplits; block 256 = 4 waves (2x2), tile 128x128, BK=64.
// A: distance-2 prefetch in regs (Ra/Rb), loads stay in flight across raw s_barriers.
// B: distance-1 via global_load_lds (smB dbuf) — WtS is L2/L3-resident, short latency.
// Per-step wait: s_waitcnt vmcnt(8) (keeps A-(t+1)'s 8 loads flying) + lgkmcnt(0).
// No sched_barrier pins (m141 lesson). LDS 48KB.
__global__ __launch_bounds__(256, 2) void gemm1(const float* __restrict__ ep,
                                                const float* __restrict__ s,
                                                const unsigned short* __restrict__ WtS,
                                                float* __restrict__ part) {
    __shared__ __align__(16) unsigned char smA[128 * 64 * 2];        // 16KB
    __shared__ __align__(16) unsigned char smB[2][128 * 64 * 2];     // 32KB

    const int bid = blockIdx.x;
    const int ks = bid / 65;
    const int mt = bid % 65;
    const int tid = threadIdx.x;
    const int kBase = ks * (KSTEPS * BK);
    const int chunkBase = ks * KSTEPS;

    const int mBase = tid >> 4;            // 0..15
    const int kOff = (tid & 15) * 4;       // f32 elems within BK
    const int swzW = (mBase & 7) << 4;

    const bool last = (mt == 64);
    const int rowBase = mt * 128;

    const int w = tid >> 6;
    const int lane = tid & 63;

    // A source row pointers — ALWAYS 8 loads/thread (uniform per-wave vmcnt accounting,
    // even in the tail block: rows > NEP load a dummy (s) and are zeroed at ds_write)
    const float* aSrc[8];
#pragma unroll
    for (int i = 0; i < 8; ++i) {
        const int rg = rowBase + mBase + i * 16;
        if (!last)            aSrc[i] = ep + (size_t)rg * STATE_DIM;
        else if (rg < NEP)    aSrc[i] = ep + (size_t)rg * STATE_DIM;
        else                  aSrc[i] = s;     // rg==NEP real, rg>NEP dummy
    }

    float4 Ra[8], Rb[8];

    auto loadA = [&](float4* R, int kc) {
#pragma unroll
        for (int i = 0; i < 8; ++i)
            R[i] = *reinterpret_cast<const float4*>(aSrc[i] + kc + kOff);
    };

    auto stageB = [&](int chunkIdx, int buf) {
        const char* cb = (const char*)(WtS + (size_t)chunkIdx * 8192);
#pragma unroll
        for (int r2 = 0; r2 < 4; ++r2) {
            const int off = ((r2 << 2) + w) << 10;      // wave-uniform byte offset
            glds16(cb + off + (lane << 4), &smB[buf][off]);
        }
    };

    auto writeLdsA = [&](const float4* R) {
#pragma unroll
        for (int i = 0; i < 8; ++i) {
            float4 a = R[i];
            if (last) {
                const int rg = rowBase + mBase + i * 16;
                if (rg > NEP) a = make_float4(0.f, 0.f, 0.f, 0.f);
            }
            u16x4 av;
            av[0] = f2bf(a.x); av[1] = f2bf(a.y);
            av[2] = f2bf(a.z); av[3] = f2bf(a.w);
            const int ad = ((mBase + i * 16) * 128 + kOff * 2) ^ swzW;
            *reinterpret_cast<u16x4*>(smA + ad) = av;
        }
    };

    const int wr = w >> 1, wc = w & 1;     // wave -> 64x64 quadrant
    const int l15 = lane & 15, lq = lane >> 4;
    const int swzF = (l15 & 7) << 4;

    f32x4 acc[4][4] = {};

    auto compute = [&](int buf) {
#pragma unroll
        for (int kh = 0; kh < 2; ++kh) {
            bf16x8 af[4], bf[4];
#pragma unroll
            for (int mf = 0; mf < 4; ++mf) {
                const int row = wr * 64 + mf * 16 + l15;
                const int ad = (row * 128 + (kh * 32 + lq * 8) * 2) ^ swzF;
                af[mf] = *reinterpret_cast<const bf16x8*>(smA + ad);
            }
#pragma unroll
            for (int nf = 0; nf < 4; ++nf) {
                const int row = wc * 64 + nf * 16 + l15;
                const int ad = (row * 128 + (kh * 32 + lq * 8) * 2) ^ swzF;
                bf[nf] = *reinterpret_cast<const bf16x8*>(smB[buf] + ad);
            }
#pragma unroll
            for (int mf = 0; mf < 4; ++mf)
#pragma unroll
                for (int nf = 0; nf < 4; ++nf)
                    acc[mf][nf] = __builtin_amdgcn_mfma_f32_16x16x32_bf16(
                        af[mf], bf[nf], acc[mf][nf], 0, 0, 0);
        }
    };

    // prologue (issue order matters for vmcnt accounting: A-0, B-0, then A-1 LAST)
    loadA(Ra, kBase);                 // A-0  (8)
    stageB(chunkBase, 0);             // B-0  (4)
    loadA(Rb, kBase + BK);            // A-1  (8)

    int buf = 0;
    for (int t2 = 0; t2 < KSTEPS; ++t2) {
        // Complete A-t and B-t (oldest); keep A-(t+1)'s 8 loads in flight.
        // lgkmcnt(0): all prior ds_reads done -> safe to overwrite smA / stream into smB.
        if (t2 + 1 < KSTEPS) { asm volatile("s_waitcnt vmcnt(8) lgkmcnt(0)" ::: "memory"); }
        else                 { asm volatile("s_waitcnt vmcnt(0) lgkmcnt(0)" ::: "memory"); }
        __builtin_amdgcn_s_barrier();              // (a) smB[buf] ready; smA free
        if (t2 & 1) writeLdsA(Rb); else writeLdsA(Ra);
        asm volatile("s_waitcnt lgkmcnt(0)" ::: "memory");
        __builtin_amdgcn_s_barrier();              // (b) smA ready
        if (t2 + 1 < KSTEPS) stageB(chunkBase + t2 + 1, buf ^ 1);   // B-(t+1): L2-latency
        if (t2 + 2 < KSTEPS) {                                      // A-(t+2): 2-step cover
            if (t2 & 1) loadA(Rb, kBase + (t2 + 2) * BK);
            else        loadA(Ra, kBase + (t2 + 2) * BK);
        }
        compute(buf);
        buf ^= 1;
    }

    // epilogue: f32 partial tile -> part[ks][rowBase + r][c]
    float* po = part + ((size_t)ks * MPAD + rowBase) * 128;
#pragma unroll
    for (int mf = 0; mf < 4; ++mf)
#pragma unroll
        for (int nf = 0; nf < 4; ++nf)
#pragma unroll
            for (int v = 0; v < 4; ++v) {
                const int row = wr * 64 + mf * 16 + lq * 4 + v;
                const int col = wc * 64 + nf * 16 + l15;
                po[(size_t)row * 128 + col] = acc[mf][nf][v];
            }
}

// ---------------- kernel 2: reduce partials + bias/relu + layers 2,3 ----------------
__global__ __launch_bounds__(256) void mlp23(const float* __restrict__ part,
                                             const float* __restrict__ b1,
                                             const float* __restrict__ W2,
                                             const float* __restrict__ b2,
                                             const float* __restrict__ W3,
                                             const float* __restrict__ b3,
                                             float* __restrict__ z) {
    __shared__ float W2t[64 * 129];
    __shared__ float W3t[32 * 65];
    __shared__ float b1L[128], b2L[64], b3L[32];
    __shared__ float h1buf[4][128];
    __shared__ float h2buf[4][64];

    const int tid = threadIdx.x;
#pragma unroll
    for (int i = 0; i < 32; ++i) {
        int f = tid + i * 256;             // f = k*64 + j
        W2t[(f & 63) * 129 + (f >> 6)] = W2[f];
    }
#pragma unroll
    for (int i = 0; i < 8; ++i) {
        int f = tid + i * 256;             // f = k*32 + c
        W3t[(f & 31) * 65 + (f >> 5)] = W3[f];
    }
    if (tid < 128) b1L[tid] = b1[tid];
    if (tid < 64) b2L[tid] = b2[tid];
    if (tid < 32) b3L[tid] = b3[tid];
    __syncthreads();

    const int w = tid >> 6, l = tid & 63;
    const int base = blockIdx.x * 16 + w * 4;
    for (int rr = 0; rr < 4; ++rr) {
        const int r = base + rr;
        if (r > NEP) continue;             // rows 0..8191 = episode, 8192 = s
        float h1a = b1L[l], h1b = b1L[l + 64];
#pragma unroll
        for (int p = 0; p < KSPLIT; ++p) {
            const float* pp = part + ((size_t)p * MPAD + r) * 128;
            h1a += pp[l];
            h1b += pp[l + 64];
        }
        h1a = fmaxf(h1a, 0.f);
        h1b = fmaxf(h1b, 0.f);
        h1buf[w][l] = h1a;
        h1buf[w][l + 64] = h1b;            // wave-synchronous LDS
        float s0 = 0.f, s1 = 0.f, s2 = 0.f, s3 = 0.f;
        const float* wr2 = &W2t[l * 129];
        const float* hb = h1buf[w];
#pragma unroll 8
        for (int k = 0; k < 32; ++k) {
            s0 += hb[k]      * wr2[k];
            s1 += hb[k + 32] * wr2[k + 32];
            s2 += hb[k + 64] * wr2[k + 64];
            s3 += hb[k + 96] * wr2[k + 96];
        }
        float a2 = fmaxf(b2L[l] + ((s0 + s1) + (s2 + s3)), 0.f);
        h2buf[w][l] = a2;
        const int c = l & 31;
        const float* wr3 = &W3t[c * 65];
        const float* h2 = h2buf[w];
        float t0 = 0.f, t1 = 0.f;
#pragma unroll 8
        for (int k = 0; k < 32; ++k) {
            t0 += h2[k]      * wr3[k];
            t1 += h2[k + 32] * wr3[k + 32];
        }
        if (l < 32) z[(size_t)r * 32 + c] = b3L[c] + t0 + t1;
    }
}

// ---------------- kernel 3: parallel distances ----------------
__global__ __launch_bounds__(256) void dist_k(const float* __restrict__ z,
                                              float* __restrict__ dist) {
    __shared__ float zs[32];
    const int t = threadIdx.x;
    if (t < 32) zs[t] = z[(size_t)NEP * 32 + t];
    __syncthreads();
    const int r = blockIdx.x * 256 + t;
    const float* zr = z + (size_t)r * 32;
    float d2 = 0.f;
#pragma unroll
    for (int c2 = 0; c2 < 32; ++c2) {
        const float d = zr[c2] - zs[c2];
        d2 += d * d;
    }
    dist[r] = sqrtf(d2);
}

// ---------------- kernel 4: top-10 extraction + scalars ----------------
__global__ __launch_bounds__(256) void top10_k(const float* __restrict__ dist,
                                               const float* __restrict__ dm2,
                                               float* __restrict__ out) {
    const int t = threadIdx.x;
    float v[32];
#pragma unroll
    for (int i = 0; i < 32; ++i) v[i] = dist[i * 256 + t];

    __shared__ float wv[4];
    __shared__ int wi[4];

    const float dm = dm2[0];
    float sd = 0.f, sk = 0.f;

    for (int round = 0; round < 10; ++round) {
        float bv = 3.0e38f;
        int bi = 0x7fffffff;
#pragma unroll
        for (int i = 0; i < 32; ++i) {
            const float x = v[i];
            const int idx = i * 256 + t;
            if (x < bv) { bv = x; bi = idx; }
        }
#pragma unroll
        for (int sft = 1; sft < 64; sft <<= 1) {
            const float ov = __shfl_xor(bv, sft);
            const int oi = __shfl_xor(bi, sft);
            if (ov < bv || (ov == bv && oi < bi)) { bv = ov; bi = oi; }
        }
        const int wid = t >> 6;
        if ((t & 63) == 0) { wv[wid] = bv; wi[wid] = bi; }
        __syncthreads();
        bv = wv[0]; bi = wi[0];
#pragma unroll
        for (int k = 1; k < 4; ++k) {
            const float ov = wv[k]; const int oi = wi[k];
            if (ov < bv || (ov == bv && oi < bi)) { bv = ov; bi = oi; }
        }
        __syncthreads();
#pragma unroll
        for (int i = 0; i < 32; ++i)
            if (bi == i * 256 + t) v[i] = 3.0e38f;
        sd += bv;
        sk += EPSK / (bv / dm + EPSK);
    }

    if (t == 0) {
        const float meand = sd * 0.1f;
        const float meank = sk * 0.1f;
        out[0] = 1.0f / (sqrtf(meank) + CC);
        out[1] = 0.99f * dm + 0.01f * meand;
    }
}

extern "C" void kernel_launch(void* const* d_in, const int* in_sizes, int n_in,
                              void* d_out, int out_size, void* d_ws, size_t ws_size,
                              hipStream_t stream) {
    const float* s   = (const float*)d_in[0];
    const float* ep  = (const float*)d_in[1];
    const float* dm2 = (const float*)d_in[2];
    const float* W1  = (const float*)d_in[3];
    const float* b1  = (const float*)d_in[4];
    const float* W2  = (const float*)d_in[5];
    const float* b2  = (const float*)d_in[6];
    const float* W3  = (const float*)d_in[7];
    const float* b3  = (const float*)d_in[8];
    float* out = (float*)d_out;

    if (ws_size < (size_t)WS_NEEDED) return;

    unsigned short* WtS = (unsigned short*)d_ws;
    float* part = (float*)((char*)d_ws + WT_BYTES);
    float* zbuf = (float*)((char*)d_ws + WT_BYTES + PART_BYTES);
    float* dist = (float*)((char*)d_ws + WT_BYTES + PART_BYTES + Z_BYTES);

    hipLaunchKernelGGL(prep_wt, dim3(441), dim3(256), 0, stream, W1, WtS);
    hipLaunchKernelGGL(gemm1, dim3(65 * KSPLIT), dim3(256), 0, stream, ep, s, WtS, part);
    hipLaunchKernelGGL(mlp23, dim3(MPAD / 16), dim3(256), 0, stream, part, b1, W2, b2, W3, b3, zbuf);
    hipLaunchKernelGGL(dist_k, dim3(32), dim3(256), 0, stream, zbuf, dist);
    hipLaunchKernelGGL(top10_k, dim3(1), dim3(256), 0, stream, dist, dm2, out);
}

// Round 8
// 227.804 us; speedup vs baseline: 1.1159x; 1.1159x over previous
//
#include <hip/hip_runtime.h>
#include <hip/hip_bf16.h>

typedef __attribute__((ext_vector_type(8))) __bf16 bf16x8;
typedef __attribute__((ext_vector_type(4))) float f32x4;
typedef __attribute__((ext_vector_type(4))) unsigned short u16x4;

#define STATE_DIM 28224
#define NEP 8192
#define MPAD 8320          // 65 * 128
#define KSPLIT 7
#define KSTEPS 63          // 28224 / (7*64)
#define BK 64
#define NWG (65 * KSPLIT)  // 455
#define EPSK 0.001f
#define CC 0.001f

// ws layout
#define WT_BYTES   (441 * 8192 * 2)                  // 7,225,344 (swizzled bf16 chunks)
#define PART_BYTES (KSPLIT * MPAD * 128 * 2)         // 14,909,440 (bf16 partials)
#define Z_BYTES    (MPAD * 32 * 4)                   // 1,064,960
#define DIST_BYTES (NEP * 4)
#define WS_NEEDED  (WT_BYTES + PART_BYTES + Z_BYTES + DIST_BYTES)

__device__ __forceinline__ unsigned short f2bf(float f) {
    unsigned int u = __float_as_uint(f);
    u += 0x7fffu + ((u >> 16) & 1u);   // RNE
    return (unsigned short)(u >> 16);
}

__device__ __forceinline__ void glds16(const void* g, void* l) {
    __builtin_amdgcn_global_load_lds(
        (const __attribute__((address_space(1))) unsigned int*)g,
        (__attribute__((address_space(3))) unsigned int*)l, 16, 0, 0);
}

// ---------------- kernel 0: W1 [28224][128] f32 -> WtS: 441 chunks of 16KB,
// chunk = swizzled bf16 image of B-tile [n=0..127][k=0..63],
// byte addr within chunk = (n*128 + k*2) ^ ((n&7)<<4)  (matches gemm ds_read swizzle)
__global__ __launch_bounds__(256) void prep_wt(const float* __restrict__ W1,
                                               unsigned short* __restrict__ WtS) {
    __shared__ __align__(16) unsigned short img[8192];
    const int c = blockIdx.x;          // 441 k-tiles
    const int tid = threadIdx.x;
    const int k0 = c * 64;
#pragma unroll
    for (int i = 0; i < 32; ++i) {
        const int f = i * 256 + tid;   // f = k*128 + n
        const int k = f >> 7, n = f & 127;
        const float wv = W1[(size_t)(k0 + k) * 128 + n];
        const int ad = ((n * 128 + k * 2) ^ ((n & 7) << 4)) >> 1;  // u16 index
        img[ad] = f2bf(wv);
    }
    __syncthreads();
    unsigned short* dst = WtS + (size_t)c * 8192;
#pragma unroll
    for (int i = 0; i < 4; ++i) {
        const int f = i * 256 + tid;   // 16B unit, 1024 total
        *reinterpret_cast<uint4*>(dst + f * 8) =
            *reinterpret_cast<const uint4*>(img + f * 8);
    }
}

// ---------------- kernel 1: split-K bf16 MFMA GEMM (R2 structure, proven 228.5) ----------
// grid = 455; block 256 = 4 waves (2x2), tile 128x128, BK=64.
// Changes vs R2: (a) bijective XCD-chunked bid swizzle (each XCD's L2 holds ~one ks-range
// of WtS -> B staging L2-hit), (b) bf16 partial output (halves part traffic).
__global__ __launch_bounds__(256, 2) void gemm1(const float* __restrict__ ep,
                                                const float* __restrict__ s,
                                                const unsigned short* __restrict__ WtS,
                                                unsigned short* __restrict__ part) {
    __shared__ __align__(16) unsigned char smA[128 * 64 * 2];
    __shared__ __align__(16) unsigned char smB[2][128 * 64 * 2];

    // bijective XCD swizzle (nwg=455, q=56, r=7)
    const int hw = blockIdx.x;
    const int xcd = hw & 7, slot = hw >> 3;
    const int q = NWG >> 3, r = NWG & 7;
    const int bid = (xcd < r ? xcd * (q + 1) : r * (q + 1) + (xcd - r) * q) + slot;

    const int ks = bid / 65;
    const int mt = bid % 65;
    const int tid = threadIdx.x;
    const int kBase = ks * (KSTEPS * BK);
    const int chunkBase = ks * KSTEPS;

    const int mBase = tid >> 4;            // 0..15
    const int kOff = (tid & 15) * 4;       // f32 elems within BK
    const int swzW = (mBase & 7) << 4;

    const bool last = (mt == 64);
    const int rowBase = mt * 128;

    float4 aR[8];

    auto loadA = [&](int kc) {
#pragma unroll
        for (int i = 0; i < 8; ++i) {
            const int m = mBase + i * 16;
            const int rg = rowBase + m;
            if (!last) {
                aR[i] = *reinterpret_cast<const float4*>(ep + (size_t)rg * STATE_DIM + kc + kOff);
            } else {
                if (rg < NEP)
                    aR[i] = *reinterpret_cast<const float4*>(ep + (size_t)rg * STATE_DIM + kc + kOff);
                else if (rg == NEP)
                    aR[i] = *reinterpret_cast<const float4*>(s + kc + kOff);
                else
                    aR[i] = make_float4(0.f, 0.f, 0.f, 0.f);
            }
        }
    };

    const int w = tid >> 6;
    const int lane = tid & 63;

    auto stageB = [&](int chunkIdx, int buf) {
        const char* cb = (const char*)(WtS + (size_t)chunkIdx * 8192);
#pragma unroll
        for (int r2 = 0; r2 < 4; ++r2) {
            const int off = ((r2 << 2) + w) << 10;      // wave-uniform byte offset
            glds16(cb + off + (lane << 4), &smB[buf][off]);
        }
    };

    auto writeLdsA = [&]() {
#pragma unroll
        for (int i = 0; i < 8; ++i) {
            const int m = mBase + i * 16;
            u16x4 av;
            av[0] = f2bf(aR[i].x); av[1] = f2bf(aR[i].y);
            av[2] = f2bf(aR[i].z); av[3] = f2bf(aR[i].w);
            const int ad = (m * 128 + kOff * 2) ^ swzW;
            *reinterpret_cast<u16x4*>(smA + ad) = av;
        }
    };

    const int wr = w >> 1, wc = w & 1;     // wave -> 64x64 quadrant
    const int l15 = lane & 15, lq = lane >> 4;
    const int swzF = (l15 & 7) << 4;

    f32x4 acc[4][4] = {};

    auto compute = [&](int buf) {
#pragma unroll
        for (int kh = 0; kh < 2; ++kh) {
            bf16x8 af[4], bf[4];
#pragma unroll
            for (int mf = 0; mf < 4; ++mf) {
                const int row = wr * 64 + mf * 16 + l15;
                const int ad = (row * 128 + (kh * 32 + lq * 8) * 2) ^ swzF;
                af[mf] = *reinterpret_cast<const bf16x8*>(smA + ad);
            }
#pragma unroll
            for (int nf = 0; nf < 4; ++nf) {
                const int row = wc * 64 + nf * 16 + l15;
                const int ad = (row * 128 + (kh * 32 + lq * 8) * 2) ^ swzF;
                bf[nf] = *reinterpret_cast<const bf16x8*>(smB[buf] + ad);
            }
#pragma unroll
            for (int mf = 0; mf < 4; ++mf)
#pragma unroll
                for (int nf = 0; nf < 4; ++nf)
                    acc[mf][nf] = __builtin_amdgcn_mfma_f32_16x16x32_bf16(
                        af[mf], bf[nf], acc[mf][nf], 0, 0, 0);
        }
    };

    loadA(kBase);
    stageB(chunkBase, 0);
    int buf = 0;
    for (int t2 = 0; t2 < KSTEPS; ++t2) {
        __syncthreads();          // (a) drains in-flight loads; prev compute done with LDS
        writeLdsA();
        __syncthreads();          // (b)
        if (t2 + 1 < KSTEPS) {    // next-step loads: in flight across compute
            loadA(kBase + (t2 + 1) * BK);
            stageB(chunkBase + t2 + 1, buf ^ 1);
        }
        compute(buf);
        buf ^= 1;
    }

    // epilogue: bf16 partial tile -> part[ks][rowBase + r][c]
    unsigned short* po = part + ((size_t)ks * MPAD + rowBase) * 128;
#pragma unroll
    for (int mf = 0; mf < 4; ++mf)
#pragma unroll
        for (int nf = 0; nf < 4; ++nf)
#pragma unroll
            for (int v = 0; v < 4; ++v) {
                const int row = wr * 64 + mf * 16 + lq * 4 + v;
                const int col = wc * 64 + nf * 16 + l15;
                po[(size_t)row * 128 + col] = f2bf(acc[mf][nf][v]);
            }
}

// ---------------- kernel 2: reduce bf16 partials + bias/relu + layers 2,3 ----------------
// lane l owns cols 2l, 2l+1 (uint = 2 x bf16 vector load per plane)
__global__ __launch_bounds__(256) void mlp23(const unsigned short* __restrict__ part,
                                             const float* __restrict__ b1,
                                             const float* __restrict__ W2,
                                             const float* __restrict__ b2,
                                             const float* __restrict__ W3,
                                             const float* __restrict__ b3,
                                             float* __restrict__ z) {
    __shared__ float W2t[64 * 129];
    __shared__ float W3t[32 * 65];
    __shared__ float b1L[128], b2L[64], b3L[32];
    __shared__ float h1buf[4][128];
    __shared__ float h2buf[4][64];

    const int tid = threadIdx.x;
#pragma unroll
    for (int i = 0; i < 32; ++i) {
        int f = tid + i * 256;             // f = k*64 + j
        W2t[(f & 63) * 129 + (f >> 6)] = W2[f];
    }
#pragma unroll
    for (int i = 0; i < 8; ++i) {
        int f = tid + i * 256;             // f = k*32 + c
        W3t[(f & 31) * 65 + (f >> 5)] = W3[f];
    }
    if (tid < 128) b1L[tid] = b1[tid];
    if (tid < 64) b2L[tid] = b2[tid];
    if (tid < 32) b3L[tid] = b3[tid];
    __syncthreads();

    const unsigned int* pu = (const unsigned int*)part;   // 2 bf16 per uint
    const int w = tid >> 6, l = tid & 63;
    const int base = blockIdx.x * 16 + w * 4;
    for (int rr = 0; rr < 4; ++rr) {
        const int r = base + rr;
        if (r > NEP) continue;             // rows 0..8191 = episode, 8192 = s
        float h1a = b1L[2 * l], h1b = b1L[2 * l + 1];
#pragma unroll
        for (int p = 0; p < KSPLIT; ++p) {
            const unsigned int u = pu[((size_t)p * MPAD + r) * 64 + l];
            h1a += __uint_as_float(u << 16);
            h1b += __uint_as_float(u & 0xffff0000u);
        }
        h1a = fmaxf(h1a, 0.f);
        h1b = fmaxf(h1b, 0.f);
        *reinterpret_cast<float2*>(&h1buf[w][2 * l]) = make_float2(h1a, h1b);
        // layer 2: 4-way split accumulators
        float s0 = 0.f, s1 = 0.f, s2 = 0.f, s3 = 0.f;
        const float* wr2 = &W2t[l * 129];
        const float* hb = h1buf[w];
#pragma unroll 8
        for (int k = 0; k < 32; ++k) {
            s0 += hb[k]      * wr2[k];
            s1 += hb[k + 32] * wr2[k + 32];
            s2 += hb[k + 64] * wr2[k + 64];
            s3 += hb[k + 96] * wr2[k + 96];
        }
        float a2 = fmaxf(b2L[l] + ((s0 + s1) + (s2 + s3)), 0.f);
        h2buf[w][l] = a2;
        // layer 3: 2-way split
        const int c = l & 31;
        const float* wr3 = &W3t[c * 65];
        const float* h2 = h2buf[w];
        float t0 = 0.f, t1 = 0.f;
#pragma unroll 8
        for (int k = 0; k < 32; ++k) {
            t0 += h2[k]      * wr3[k];
            t1 += h2[k + 32] * wr3[k + 32];
        }
        if (l < 32) z[(size_t)r * 32 + c] = b3L[c] + t0 + t1;
    }
}

// ---------------- kernel 3: parallel distances ----------------
__global__ __launch_bounds__(256) void dist_k(const float* __restrict__ z,
                                              float* __restrict__ dist) {
    __shared__ float zs[32];
    const int t = threadIdx.x;
    if (t < 32) zs[t] = z[(size_t)NEP * 32 + t];
    __syncthreads();
    const int r = blockIdx.x * 256 + t;
    const float* zr = z + (size_t)r * 32;
    float d2 = 0.f;
#pragma unroll
    for (int c2 = 0; c2 < 32; ++c2) {
        const float d = zr[c2] - zs[c2];
        d2 += d * d;
    }
    dist[r] = sqrtf(d2);
}

// ---------------- kernel 4: top-10 extraction + scalars ----------------
__global__ __launch_bounds__(256) void top10_k(const float* __restrict__ dist,
                                               const float* __restrict__ dm2,
                                               float* __restrict__ out) {
    const int t = threadIdx.x;
    float v[32];
#pragma unroll
    for (int i = 0; i < 32; ++i) v[i] = dist[i * 256 + t];

    __shared__ float wv[4];
    __shared__ int wi[4];

    const float dm = dm2[0];
    float sd = 0.f, sk = 0.f;

    for (int round = 0; round < 10; ++round) {
        float bv = 3.0e38f;
        int bi = 0x7fffffff;
#pragma unroll
        for (int i = 0; i < 32; ++i) {
            const float x = v[i];
            const int idx = i * 256 + t;
            if (x < bv) { bv = x; bi = idx; }
        }
#pragma unroll
        for (int sft = 1; sft < 64; sft <<= 1) {
            const float ov = __shfl_xor(bv, sft);
            const int oi = __shfl_xor(bi, sft);
            if (ov < bv || (ov == bv && oi < bi)) { bv = ov; bi = oi; }
        }
        const int wid = t >> 6;
        if ((t & 63) == 0) { wv[wid] = bv; wi[wid] = bi; }
        __syncthreads();
        bv = wv[0]; bi = wi[0];
#pragma unroll
        for (int k = 1; k < 4; ++k) {
            const float ov = wv[k]; const int oi = wi[k];
            if (ov < bv || (ov == bv && oi < bi)) { bv = ov; bi = oi; }
        }
        __syncthreads();
#pragma unroll
        for (int i = 0; i < 32; ++i)
            if (bi == i * 256 + t) v[i] = 3.0e38f;
        sd += bv;
        sk += EPSK / (bv / dm + EPSK);
    }

    if (t == 0) {
        const float meand = sd * 0.1f;
        const float meank = sk * 0.1f;
        out[0] = 1.0f / (sqrtf(meank) + CC);
        out[1] = 0.99f * dm + 0.01f * meand;
    }
}

extern "C" void kernel_launch(void* const* d_in, const int* in_sizes, int n_in,
                              void* d_out, int out_size, void* d_ws, size_t ws_size,
                              hipStream_t stream) {
    const float* s   = (const float*)d_in[0];
    const float* ep  = (const float*)d_in[1];
    const float* dm2 = (const float*)d_in[2];
    const float* W1  = (const float*)d_in[3];
    const float* b1  = (const float*)d_in[4];
    const float* W2  = (const float*)d_in[5];
    const float* b2  = (const float*)d_in[6];
    const float* W3  = (const float*)d_in[7];
    const float* b3  = (const float*)d_in[8];
    float* out = (float*)d_out;

    if (ws_size < (size_t)WS_NEEDED) return;

    unsigned short* WtS  = (unsigned short*)d_ws;
    unsigned short* part = (unsigned short*)((char*)d_ws + WT_BYTES);
    float* zbuf = (float*)((char*)d_ws + WT_BYTES + PART_BYTES);
    float* dist = (float*)((char*)d_ws + WT_BYTES + PART_BYTES + Z_BYTES);

    hipLaunchKernelGGL(prep_wt, dim3(441), dim3(256), 0, stream, W1, WtS);
    hipLaunchKernelGGL(gemm1, dim3(NWG), dim3(256), 0, stream, ep, s, WtS, part);
    hipLaunchKernelGGL(mlp23, dim3(MPAD / 16), dim3(256), 0, stream, part, b1, W2, b2, W3, b3, zbuf);
    hipLaunchKernelGGL(dist_k, dim3(32), dim3(256), 0, stream, zbuf, dist);
    hipLaunchKernelGGL(top10_k, dim3(1), dim3(256), 0, stream, dist, dm2, out);
}